// Round 1
// baseline (227.506 us; speedup 1.0000x reference)
//
#include <hip/hip_runtime.h>
#include <math.h>

// Pipeline:  y[b,i,j,0:16] = patch(b,i,j) · B + c   (affine collapse of FFT→ComplexDense→iFFT→Re)
//            out = subsample_odd( BN( dwconv3x3(y) ) )
//
// ws layout (floats):
//   [0      .. 4095 ] Bt[16][256]   (B transposed, written by k_precompB)
//   [4096   .. 4111 ] c[16]         (written by k_precompV)
//   [4128   .. 8223 ] ReV[256][16]  (written by k_precompV)
//   [8224   .. 12319] ImV[256][16]  (written by k_precompV)
//   [12320  .. +2M  ] y[2][256][256][16]
// total = 8,405,056 bytes

constexpr int BT_OFF  = 0;
constexpr int C_OFF   = 4096;
constexpr int REV_OFF = 4128;
constexpr int IMV_OFF = 8224;
constexpr int Y_OFF   = 12320;

#define TWO_PI_OVER_256 0.0245436926f
#define BN_EPS 1e-5f

#define FMA4(ACC, A, B) \
  ACC = fmaf((A).x, (B).x, ACC); ACC = fmaf((A).y, (B).y, ACC); \
  ACC = fmaf((A).z, (B).z, ACC); ACC = fmaf((A).w, (B).w, ACC);

// ---------------- A1: V[k][d] = (1/16) sum_j W[k][j] e^{+2pi i jd/16};  also c[d] ---------------
__global__ __launch_bounds__(256) void k_precompV(
    const float* __restrict__ Wr, const float* __restrict__ br,
    const float* __restrict__ Wi, const float* __restrict__ bi,
    float* __restrict__ ws) {
  __shared__ float cs[256], sn[256];
  int tid = threadIdx.x;
  float s_, c_;
  sincosf((float)tid * TWO_PI_OVER_256, &s_, &c_);
  cs[tid] = c_; sn[tid] = s_;
  __syncthreads();

  int tg = blockIdx.x * 256 + tid;     // 0..4095
  int k = tg >> 4, d = tg & 15;
  float re = 0.f, im = 0.f;
#pragma unroll
  for (int j = 0; j < 16; ++j) {
    float wr = Wr[k * 16 + j], wi = Wi[k * 16 + j];
    int idx = ((j * d) & 15) << 4;     // angle 2pi*(jd)/16
    float cc = cs[idx], ss = sn[idx];
    re += wr * cc - wi * ss;
    im += wr * ss + wi * cc;
  }
  ws[REV_OFF + tg] = re * 0.0625f;
  ws[IMV_OFF + tg] = im * 0.0625f;

  if (blockIdx.x == 0 && tid < 16) {   // c[d]
    float acc = 0.f;
#pragma unroll
    for (int j = 0; j < 16; ++j) {
      float cr  = br[j] - bi[j];       // Re(beta)
      float ci2 = br[j] + bi[j];       // Im(beta)
      int idx = ((j * tid) & 15) << 4;
      acc += cr * cs[idx] - ci2 * sn[idx];
    }
    ws[C_OFF + tid] = acc * 0.0625f;
  }
}

// ---------------- A2: Bt[d][n] = sum_k ReV[k][d] cos(2pi kn/256) + ImV[k][d] sin(2pi kn/256) ----
__global__ __launch_bounds__(256) void k_precompB(float* __restrict__ ws) {
  __shared__ float cs[256], sn[256];
  int tid = threadIdx.x;
  float s_, c_;
  sincosf((float)tid * TWO_PI_OVER_256, &s_, &c_);
  cs[tid] = c_; sn[tid] = s_;
  __syncthreads();

  int e = tid >> 2, q = tid & 3;       // 4 lanes cooperate per (n,d) entry
  int eg = blockIdx.x * 64 + e;        // 0..4095
  int n = eg >> 4, d = eg & 15;
  const float* ReV = ws + REV_OFF;
  const float* ImV = ws + IMV_OFF;
  int m = (q * n) & 255;
  int step = (n << 2) & 255;
  float acc = 0.f;
#pragma unroll 4
  for (int kk = 0; kk < 64; ++kk) {
    int k = q + (kk << 2);
    acc = fmaf(ReV[k * 16 + d], cs[m], acc);
    acc = fmaf(ImV[k * 16 + d], sn[m], acc);
    m = (m + step) & 255;
  }
  acc += __shfl_xor(acc, 1);
  acc += __shfl_xor(acc, 2);
  if (q == 0) ws[BT_OFF + d * 256 + n] = acc;
}

// ---------------- B: patch GEMM  y = p·B + c --------------------------------------------------
// grid 1024 = b(2) x i(256) x half(2); 128 threads; block covers 128 patches x 16 ch.
// Per thread: 4 patches x 4 channels register tile. x staged per patch-row (double-buffered,
// +4/64-word padding to kill the stride-64 bank conflict). Bt padded to 260 floats/row.
__global__ __launch_bounds__(128) void k_patch_gemm(
    const float* __restrict__ x, float* __restrict__ ws) {
  __shared__ __align__(16) float xs[2][2176];     // 2048 + 32*4 pad
  __shared__ __align__(16) float Btl[16 * 260];
  __shared__ __align__(16) float cl[16];

  int tid = threadIdx.x;
  int blk = blockIdx.x;
  int half = blk & 1;
  int i = (blk >> 1) & 255;
  int b = blk >> 9;

  const float* xbase = x + ((b * 4096 + i * 16) * 4096 + half * 2048);

  // load Bt -> LDS (padded rows)
#pragma unroll
  for (int it = 0; it < 8; ++it) {
    int flat = it * 512 + tid * 4;
    float4 v = *reinterpret_cast<const float4*>(ws + BT_OFF + flat);
    int d = flat >> 8, n = flat & 255;
    *reinterpret_cast<float4*>(&Btl[d * 260 + n]) = v;
  }
  if (tid < 16) cl[tid] = ws[C_OFF + tid];

  // stage row 0
#pragma unroll
  for (int it = 0; it < 4; ++it) {
    int w = it * 512 + tid * 4;
    float4 v = *reinterpret_cast<const float4*>(xbase + w);
    *reinterpret_cast<float4*>(&xs[0][w + ((w >> 6) << 2)]) = v;
  }
  __syncthreads();

  int jg = tid >> 2, dg = tid & 3;
  int xoff = jg * 68;                  // padded base of this thread's 4 patches
  int boff = dg * 4 * 260;

  float acc[4][4];
#pragma unroll
  for (int u = 0; u < 4; ++u)
#pragma unroll
    for (int v = 0; v < 4; ++v) acc[u][v] = 0.f;

  for (int r = 0; r < 16; ++r) {
    float4 st0, st1, st2, st3;
    if (r < 15) {                      // issue next-row loads early (latency hidden by compute)
      const float* rowp = xbase + (r + 1) * 4096;
      st0 = *reinterpret_cast<const float4*>(rowp + (0 * 512 + tid * 4));
      st1 = *reinterpret_cast<const float4*>(rowp + (1 * 512 + tid * 4));
      st2 = *reinterpret_cast<const float4*>(rowp + (2 * 512 + tid * 4));
      st3 = *reinterpret_cast<const float4*>(rowp + (3 * 512 + tid * 4));
    }
    const float* xb = xs[r & 1];
#pragma unroll
    for (int s4 = 0; s4 < 16; s4 += 4) {
      const float4 a0 = *reinterpret_cast<const float4*>(xb + xoff + s4);
      const float4 a1 = *reinterpret_cast<const float4*>(xb + xoff + 16 + s4);
      const float4 a2 = *reinterpret_cast<const float4*>(xb + xoff + 32 + s4);
      const float4 a3 = *reinterpret_cast<const float4*>(xb + xoff + 48 + s4);
      const float4 b0 = *reinterpret_cast<const float4*>(Btl + boff + r * 16 + s4);
      const float4 b1 = *reinterpret_cast<const float4*>(Btl + boff + 260 + r * 16 + s4);
      const float4 b2 = *reinterpret_cast<const float4*>(Btl + boff + 520 + r * 16 + s4);
      const float4 b3 = *reinterpret_cast<const float4*>(Btl + boff + 780 + r * 16 + s4);
      FMA4(acc[0][0], a0, b0); FMA4(acc[0][1], a0, b1); FMA4(acc[0][2], a0, b2); FMA4(acc[0][3], a0, b3);
      FMA4(acc[1][0], a1, b0); FMA4(acc[1][1], a1, b1); FMA4(acc[1][2], a1, b2); FMA4(acc[1][3], a1, b3);
      FMA4(acc[2][0], a2, b0); FMA4(acc[2][1], a2, b1); FMA4(acc[2][2], a2, b2); FMA4(acc[2][3], a2, b3);
      FMA4(acc[3][0], a3, b0); FMA4(acc[3][1], a3, b1); FMA4(acc[3][2], a3, b2); FMA4(acc[3][3], a3, b3);
    }
    if (r < 15) {
      float* dst = xs[(r + 1) & 1];
      int w0 = 0 * 512 + tid * 4, w1 = 1 * 512 + tid * 4, w2 = 2 * 512 + tid * 4, w3 = 3 * 512 + tid * 4;
      *reinterpret_cast<float4*>(dst + w0 + ((w0 >> 6) << 2)) = st0;
      *reinterpret_cast<float4*>(dst + w1 + ((w1 >> 6) << 2)) = st1;
      *reinterpret_cast<float4*>(dst + w2 + ((w2 >> 6) << 2)) = st2;
      *reinterpret_cast<float4*>(dst + w3 + ((w3 >> 6) << 2)) = st3;
      __syncthreads();
    }
  }

  // epilogue: add c, store y
  const float4 cv = *reinterpret_cast<const float4*>(&cl[dg * 4]);
  int jjbase = half * 128 + jg * 4;
  int ybase = (b * 256 + i) * 256;
#pragma unroll
  for (int u = 0; u < 4; ++u) {
    float4 o;
    o.x = acc[u][0] + cv.x; o.y = acc[u][1] + cv.y;
    o.z = acc[u][2] + cv.z; o.w = acc[u][3] + cv.w;
    *reinterpret_cast<float4*>(ws + Y_OFF + (ybase + jjbase + u) * 16 + dg * 4) = o;
  }
}

// ---------------- C: depthwise 3x3 SAME + BN + odd-index subsample -----------------------------
__global__ __launch_bounds__(128) void k_conv_bn(
    const float* __restrict__ ws, const float* __restrict__ dwk,
    const float* __restrict__ dwb, const float* __restrict__ gamma,
    const float* __restrict__ beta, const float* __restrict__ mmean,
    const float* __restrict__ mvar, float* __restrict__ out) {
  int g = blockIdx.x * 128 + threadIdx.x;   // 0..32767 = b*128*128
  int oj = g & 127, oi = (g >> 7) & 127, b = g >> 14;
  int ci = 2 * oi + 1, cj = 2 * oj + 1;     // nearest-neighbor: odd indices
  const float* yb = ws + Y_OFF + b * (256 * 256 * 16);

  float acc[16];
#pragma unroll
  for (int t = 0; t < 16; ++t) acc[t] = 0.f;

#pragma unroll
  for (int kh = 0; kh < 3; ++kh) {
    int r = ci + kh - 1;
    if (r > 255) continue;                  // SAME zero-pad (only top edge can clip: r>=0 always)
#pragma unroll
    for (int kw = 0; kw < 3; ++kw) {
      int cc = cj + kw - 1;
      if (cc > 255) continue;
      const float* yp = yb + (r * 256 + cc) * 16;
      const float* kp = dwk + (kh * 3 + kw) * 16;
#pragma unroll
      for (int qq = 0; qq < 4; ++qq) {
        float4 yv = *reinterpret_cast<const float4*>(yp + qq * 4);
        float4 kv = *reinterpret_cast<const float4*>(kp + qq * 4);
        acc[qq * 4 + 0] = fmaf(yv.x, kv.x, acc[qq * 4 + 0]);
        acc[qq * 4 + 1] = fmaf(yv.y, kv.y, acc[qq * 4 + 1]);
        acc[qq * 4 + 2] = fmaf(yv.z, kv.z, acc[qq * 4 + 2]);
        acc[qq * 4 + 3] = fmaf(yv.w, kv.w, acc[qq * 4 + 3]);
      }
    }
  }

  int obase = ((b * 128 + oi) * 128 + oj) * 16;
#pragma unroll
  for (int qq = 0; qq < 4; ++qq) {
    float4 gv = *reinterpret_cast<const float4*>(gamma + qq * 4);
    float4 bv = *reinterpret_cast<const float4*>(beta + qq * 4);
    float4 mv = *reinterpret_cast<const float4*>(mmean + qq * 4);
    float4 vv = *reinterpret_cast<const float4*>(mvar + qq * 4);
    float4 dbv = *reinterpret_cast<const float4*>(dwb + qq * 4);
    float4 o;
    o.x = (acc[qq * 4 + 0] + dbv.x - mv.x) * (gv.x * rsqrtf(vv.x + BN_EPS)) + bv.x;
    o.y = (acc[qq * 4 + 1] + dbv.y - mv.y) * (gv.y * rsqrtf(vv.y + BN_EPS)) + bv.y;
    o.z = (acc[qq * 4 + 2] + dbv.z - mv.z) * (gv.z * rsqrtf(vv.z + BN_EPS)) + bv.z;
    o.w = (acc[qq * 4 + 3] + dbv.w - mv.w) * (gv.w * rsqrtf(vv.w + BN_EPS)) + bv.w;
    *reinterpret_cast<float4*>(out + obase + qq * 4) = o;
  }
}

extern "C" void kernel_launch(void* const* d_in, const int* in_sizes, int n_in,
                              void* d_out, int out_size, void* d_ws, size_t ws_size,
                              hipStream_t stream) {
  const float* x     = (const float*)d_in[0];
  const float* Wr    = (const float*)d_in[1];
  const float* br    = (const float*)d_in[2];
  const float* Wi    = (const float*)d_in[3];
  const float* bi    = (const float*)d_in[4];
  const float* dwk   = (const float*)d_in[5];
  const float* dwb   = (const float*)d_in[6];
  const float* gamma = (const float*)d_in[7];
  const float* beta  = (const float*)d_in[8];
  const float* mmean = (const float*)d_in[9];
  const float* mvar  = (const float*)d_in[10];
  float* ws  = (float*)d_ws;
  float* out = (float*)d_out;

  k_precompV<<<16, 256, 0, stream>>>(Wr, br, Wi, bi, ws);
  k_precompB<<<64, 256, 0, stream>>>(ws);
  k_patch_gemm<<<1024, 128, 0, stream>>>(x, ws);
  k_conv_bn<<<256, 128, 0, stream>>>(ws, dwk, dwb, gamma, beta, mmean, mvar, out);
}

// Round 3
// 223.675 us; speedup vs baseline: 1.0171x; 1.0171x over previous
//
#include <hip/hip_runtime.h>
#include <math.h>

// Pipeline:  y[b,i,j,0:16] = patch(b,i,j) · B + c   (affine collapse of FFT→ComplexDense→iFFT→Re)
//            out = subsample_odd( BN( dwconv3x3(y) ) )
//
// GEMM is done with v_mfma_f32_16x16x32_f16, A-fragments loaded DIRECTLY from
// global x (no LDS, no barriers): lane l of a wave owns patch m=l&15, and for
// k-chunk t its 8 elements k=32t+8*(l>>4)+i are 8 consecutive floats of one
// input row. B is precomputed into MFMA-fragment order (f16 blob in ws).
//
// ws layout (floats):
//   [0     .. 15  ]  c[16]
//   [32    .. 4127]  ReV[256][16]
//   [4128  .. 8223]  ImV[256][16]
//   [8224  .. 10271] Bfrag: 4096 f16 = 8 t-chunks x 64 lanes x 8 f16
//   [10272 .. +2M ]  y[2][256][256][16] f32

typedef _Float16 f16x8 __attribute__((ext_vector_type(8)));
typedef float    f32x4 __attribute__((ext_vector_type(4)));

constexpr int C_OFF   = 0;
constexpr int REV_OFF = 32;
constexpr int IMV_OFF = 4128;
constexpr int BF_OFF  = 8224;
constexpr int Y_OFF   = 10272;

#define TWO_PI_OVER_256 0.0245436926f
#define BN_EPS 1e-5f

// ---------------- A1: V[k][d] = (1/16) sum_j W[k][j] e^{+2pi i jd/16};  also c[d] ---------------
__global__ __launch_bounds__(256) void k_precompV(
    const float* __restrict__ Wr, const float* __restrict__ br,
    const float* __restrict__ Wi, const float* __restrict__ bi,
    float* __restrict__ ws) {
  __shared__ float cs[256], sn[256];
  int tid = threadIdx.x;
  float s_, c_;
  sincosf((float)tid * TWO_PI_OVER_256, &s_, &c_);
  cs[tid] = c_; sn[tid] = s_;
  __syncthreads();

  int tg = blockIdx.x * 256 + tid;     // 0..4095
  int k = tg >> 4, d = tg & 15;
  float re = 0.f, im = 0.f;
#pragma unroll
  for (int j = 0; j < 16; ++j) {
    float wr = Wr[k * 16 + j], wi = Wi[k * 16 + j];
    int idx = ((j * d) & 15) << 4;     // angle 2pi*(jd)/16
    float cc = cs[idx], ss = sn[idx];
    re += wr * cc - wi * ss;
    im += wr * ss + wi * cc;
  }
  ws[REV_OFF + tg] = re * 0.0625f;
  ws[IMV_OFF + tg] = im * 0.0625f;

  if (blockIdx.x == 0 && tid < 16) {   // c[d]
    float acc = 0.f;
#pragma unroll
    for (int j = 0; j < 16; ++j) {
      float cr  = br[j] - bi[j];       // Re(beta)
      float ci2 = br[j] + bi[j];       // Im(beta)
      int idx = ((j * tid) & 15) << 4;
      acc += cr * cs[idx] - ci2 * sn[idx];
    }
    ws[C_OFF + tid] = acc * 0.0625f;
  }
}

// ---------------- A2: B[n][d] -> f16 fragment blob ---------------------------------------------
// B[n][d] = sum_k ReV[k][d] cos(2pi kn/256) + ImV[k][d] sin(2pi kn/256)
// Fragment position for value (n=k-index, d=channel):
//   t = n>>5, lane = d + 16*((n>>3)&3), i = n&7  -> blob[(t*64+lane)*8 + i]
__global__ __launch_bounds__(256) void k_precompB(float* __restrict__ ws) {
  __shared__ float cs[256], sn[256];
  int tid = threadIdx.x;
  float s_, c_;
  sincosf((float)tid * TWO_PI_OVER_256, &s_, &c_);
  cs[tid] = c_; sn[tid] = s_;
  __syncthreads();

  int e = tid >> 2, q = tid & 3;       // 4 lanes cooperate per (n,d) entry
  int eg = blockIdx.x * 64 + e;        // 0..4095
  int n = eg >> 4, d = eg & 15;
  const float* ReV = ws + REV_OFF;
  const float* ImV = ws + IMV_OFF;
  int m = (q * n) & 255;
  int step = (n << 2) & 255;
  float acc = 0.f;
#pragma unroll 4
  for (int kk = 0; kk < 64; ++kk) {
    int k = q + (kk << 2);
    acc = fmaf(ReV[k * 16 + d], cs[m], acc);
    acc = fmaf(ImV[k * 16 + d], sn[m], acc);
    m = (m + step) & 255;
  }
  acc += __shfl_xor(acc, 1);
  acc += __shfl_xor(acc, 2);
  if (q == 0) {
    int t = n >> 5, hh = (n >> 3) & 3, ii = n & 7;
    _Float16* bf = (_Float16*)(ws + BF_OFF);
    bf[((t * 64 + (d + (hh << 4))) << 3) + ii] = (_Float16)acc;
  }
}

// ---------------- B: patch GEMM via MFMA, direct-to-register A ---------------------------------
// wave = one 16-patch tile (16 consecutive j in one patch-row i). 8192 waves total.
__global__ __launch_bounds__(256) void k_gemm(const float* __restrict__ x,
                                              float* __restrict__ ws) {
  int tid = threadIdx.x;
  int l   = tid & 63;
  int wv  = (blockIdx.x << 2) + (tid >> 6);  // 0..8191
  int j16 = wv & 15;
  int i   = (wv >> 4) & 255;
  int b   = wv >> 12;
  int m   = l & 15;          // A: patch-in-tile; B/D: channel
  int h   = l >> 4;

  // B fragments (coalesced, L2-resident)
  const f16x8* bfr = (const f16x8*)(ws + BF_OFF);
  f16x8 bf[8];
#pragma unroll
  for (int t = 0; t < 8; ++t) bf[t] = bfr[(t << 6) + l];

  // A: issue all 16 global float4 loads
  const float* ab = x + (b * 4096 + i * 16 + (h >> 1)) * 4096
                      + (j16 << 8) + (m << 4) + ((h & 1) << 3);
  float4 ar[8][2];
#pragma unroll
  for (int t = 0; t < 8; ++t) {
    ar[t][0] = *reinterpret_cast<const float4*>(ab + t * 8192);
    ar[t][1] = *reinterpret_cast<const float4*>(ab + t * 8192 + 4);
  }

  f32x4 acc = {0.f, 0.f, 0.f, 0.f};
#pragma unroll
  for (int t = 0; t < 8; ++t) {
    f16x8 a;
    a[0] = (_Float16)ar[t][0].x; a[1] = (_Float16)ar[t][0].y;
    a[2] = (_Float16)ar[t][0].z; a[3] = (_Float16)ar[t][0].w;
    a[4] = (_Float16)ar[t][1].x; a[5] = (_Float16)ar[t][1].y;
    a[6] = (_Float16)ar[t][1].z; a[7] = (_Float16)ar[t][1].w;
    acc = __builtin_amdgcn_mfma_f32_16x16x32_f16(a, bf[t], acc, 0, 0, 0);
  }

  // epilogue: D[row=4h+r][col=m] -> y[pix][ch] + c[ch]
  float cv = ws[C_OFF + m];
  int pixbase = (b << 16) + (i << 8) + (j16 << 4);
  float* y = ws + Y_OFF;
#pragma unroll
  for (int r = 0; r < 4; ++r) {
    int p = (h << 2) + r;
    y[(pixbase + p) * 16 + m] = acc[r] + cv;
  }
}

// ---------------- C: depthwise 3x3 SAME + BN + odd-index subsample -----------------------------
// thread = (output pixel, 4 channels). 131072 threads.
__global__ __launch_bounds__(256) void k_conv_bn(
    const float* __restrict__ ws, const float* __restrict__ dwk,
    const float* __restrict__ dwb, const float* __restrict__ gamma,
    const float* __restrict__ beta, const float* __restrict__ mmean,
    const float* __restrict__ mvar, float* __restrict__ out) {
  int g = blockIdx.x * 256 + threadIdx.x;
  int qq = g & 3;
  int pg = g >> 2;                          // 0..32767
  int oj = pg & 127, oi = (pg >> 7) & 127, b = pg >> 14;
  int ci = 2 * oi + 1, cj = 2 * oj + 1;     // nearest-neighbor: odd indices
  const float* yb = ws + Y_OFF + b * (256 * 256 * 16);

  float4 acc = {0.f, 0.f, 0.f, 0.f};
#pragma unroll
  for (int kh = 0; kh < 3; ++kh) {
    int r = ci + kh - 1;
    if (r > 255) continue;                  // SAME zero-pad (r>=0 always)
#pragma unroll
    for (int kw = 0; kw < 3; ++kw) {
      int cc = cj + kw - 1;
      if (cc > 255) continue;
      float4 yv = *reinterpret_cast<const float4*>(yb + ((r << 8) + cc) * 16 + (qq << 2));
      float4 kv = *reinterpret_cast<const float4*>(dwk + ((kh * 3 + kw) << 4) + (qq << 2));
      acc.x = fmaf(yv.x, kv.x, acc.x);
      acc.y = fmaf(yv.y, kv.y, acc.y);
      acc.z = fmaf(yv.z, kv.z, acc.z);
      acc.w = fmaf(yv.w, kv.w, acc.w);
    }
  }

  float4 gv  = *reinterpret_cast<const float4*>(gamma + (qq << 2));
  float4 bv  = *reinterpret_cast<const float4*>(beta  + (qq << 2));
  float4 mv  = *reinterpret_cast<const float4*>(mmean + (qq << 2));
  float4 vv  = *reinterpret_cast<const float4*>(mvar  + (qq << 2));
  float4 dbv = *reinterpret_cast<const float4*>(dwb   + (qq << 2));
  float4 o;
  o.x = (acc.x + dbv.x - mv.x) * (gv.x * rsqrtf(vv.x + BN_EPS)) + bv.x;
  o.y = (acc.y + dbv.y - mv.y) * (gv.y * rsqrtf(vv.y + BN_EPS)) + bv.y;
  o.z = (acc.z + dbv.z - mv.z) * (gv.z * rsqrtf(vv.z + BN_EPS)) + bv.z;
  o.w = (acc.w + dbv.w - mv.w) * (gv.w * rsqrtf(vv.w + BN_EPS)) + bv.w;
  *reinterpret_cast<float4*>(out + (pg << 4) + (qq << 2)) = o;
}

extern "C" void kernel_launch(void* const* d_in, const int* in_sizes, int n_in,
                              void* d_out, int out_size, void* d_ws, size_t ws_size,
                              hipStream_t stream) {
  const float* x     = (const float*)d_in[0];
  const float* Wr    = (const float*)d_in[1];
  const float* br    = (const float*)d_in[2];
  const float* Wi    = (const float*)d_in[3];
  const float* bi    = (const float*)d_in[4];
  const float* dwk   = (const float*)d_in[5];
  const float* dwb   = (const float*)d_in[6];
  const float* gamma = (const float*)d_in[7];
  const float* beta  = (const float*)d_in[8];
  const float* mmean = (const float*)d_in[9];
  const float* mvar  = (const float*)d_in[10];
  float* ws  = (float*)d_ws;
  float* out = (float*)d_out;

  k_precompV<<<16,   256, 0, stream>>>(Wr, br, Wi, bi, ws);
  k_precompB<<<64,   256, 0, stream>>>(ws);
  k_gemm    <<<2048, 256, 0, stream>>>(x, ws);
  k_conv_bn <<<512,  256, 0, stream>>>(ws, dwk, dwb, gamma, beta, mmean, mvar, out);
}